// Round 4
// baseline (312.813 us; speedup 1.0000x reference)
//
#include <hip/hip_runtime.h>

typedef __attribute__((ext_vector_type(8))) short bf16x8;
typedef __attribute__((ext_vector_type(4))) float f32x4;
typedef __attribute__((ext_vector_type(8))) unsigned short u16x8;

#define DEVINL __device__ __forceinline__

constexpr int NI = 256;   // input channels (K)
constexpr int NO = 256;   // output channels
constexpr int NC = 120;   // irrep feature width
constexpr int KQ = 64;    // K staged per LDS fill
constexpr int NSTAGE = NI / KQ;   // 4
constexpr int CW = 8;     // c-tile width: 120 = 15 * 8

DEVINL ushort f2bf(float x) {   // round-to-nearest-even fp32 -> bf16 bits (inputs finite)
  unsigned u = __float_as_uint(x);
  u += 0x7FFFu + ((u >> 16) & 1u);
  return (ushort)(u >> 16);
}

// ---- prep: wb[((m*32 + k/8)*256 + o)*8 + k%8] = bf16(W_m[o][k]) ----
__global__ __launch_bounds__(256) void prep_w(const float* __restrict__ w0,
                                              const float* __restrict__ w1,
                                              const float* __restrict__ w2,
                                              ushort* __restrict__ wb) {
  const int m = blockIdx.x >> 5;        // 0..55
  const int kc = blockIdx.x & 31;       // k-chunk of 8
  const int o = threadIdx.x;            // 0..255
  const float* src;
  if (m < 32)      src = w0 + ((size_t)(m * NO + o)) * NI;
  else if (m < 48) src = w1 + ((size_t)((m - 32) * NO + o)) * NI;
  else             src = w2 + ((size_t)((m - 48) * NO + o)) * NI;
  src += kc * 8;
  float4 a = *reinterpret_cast<const float4*>(src);
  float4 b = *reinterpret_cast<const float4*>(src + 4);
  u16x8 p = { f2bf(a.x), f2bf(a.y), f2bf(a.z), f2bf(a.w),
              f2bf(b.x), f2bf(b.y), f2bf(b.z), f2bf(b.w) };
  *reinterpret_cast<u16x8*>(wb + ((size_t)(blockIdx.x * 256 + o)) * 8) = p;
}

// ---- main: ONE generic body (no template switch -> I$-resident ~2.5 KB) ----
// block = 256 thr / 4 waves = [16 b] x [64 o] x [8 c], K in 4 stages via LDS.
__global__ __launch_bounds__(256, 4) void e3mix(const float* __restrict__ x,
                                                const ushort* __restrict__ wb,
                                                const float* __restrict__ bias0,
                                                float* __restrict__ out) {
  __shared__ ushort xs[CW * 16 * KQ];      // 16 KB

  const int bid = blockIdx.x;              // grid = 15 * 256 = 3840 exactly
  const int ct  = bid >> 8;                // 0..14, SLOWEST -> same code + same W slice
                                           // for all co-resident blocks on a CU
  const int rest = bid & 255;
  const int oq  = rest & 3;                // fastest -> 4 consecutive blocks share bt (x L2 reuse)
  const int bt  = rest >> 2;

  const int c0 = ct * CW;

  const int tid  = threadIdx.x;
  const int lane = tid & 63;
  const int wid  = tid >> 6;               // 4 waves, each owns 16 o-columns
  const int bg   = bt * 16;
  const int ocol = oq * 64 + wid * 16 + (lane & 15);

  const int rb = lane & 15;                // A-frag row (b)
  const int rg = lane >> 4;                // A/B-frag k-group

  // staging map: per thread 8 consecutive k x 4 c (one quad) at one b
  const int cq = tid & 1;                  // c-quad (0/1)
  const int sb = (tid >> 1) & 15;          // b row
  const int kb = tid >> 5;                 // k-block of 8 (0..7)

  f32x4 acc[CW];
#pragma unroll
  for (int i = 0; i < CW; ++i) acc[i] = (f32x4)0.0f;

#pragma unroll 1
  for (int s = 0; s < NSTAGE; ++s) {
    if (s) __syncthreads();                // all waves done reading xs before overwrite
    {
      const float* src = x + (size_t)(bg + sb) * (NI * NC)
                           + (size_t)(s * KQ + kb * 8) * NC + (c0 + 4 * cq);
      f32x4 v[8];
#pragma unroll
      for (int j = 0; j < 8; ++j) v[j] = *reinterpret_cast<const f32x4*>(src + j * NC);
#pragma unroll
      for (int c = 0; c < 4; ++c) {
        const int cc = 4 * cq + c;
        const int row = cc * 16 + sb;
        const int swz = ((sb & 7) ^ (cc & 7)) << 3;    // XOR bank swizzle on k
#pragma unroll
        for (int jq = 0; jq < 2; ++jq) {
          const int kpos = (kb * 8 + jq * 4) ^ swz;    // stays 4-aligned
          ushort4 p;
          p.x = f2bf(v[jq * 4 + 0][c]); p.y = f2bf(v[jq * 4 + 1][c]);
          p.z = f2bf(v[jq * 4 + 2][c]); p.w = f2bf(v[jq * 4 + 3][c]);
          *reinterpret_cast<ushort4*>(xs + row * KQ + kpos) = p;
        }
      }
    }
    __syncthreads();

    // runtime weight-matrix tracking: all wave-uniform (SALU + s_cbranch, no divergence)
    int mprev = -1;
    bf16x8 bw0 = {}, bw1 = {};
#pragma unroll
    for (int cc = 0; cc < CW; ++cc) {
      const int c = c0 + cc;
      const int m = c < 32 ? c : (c < 80 ? 32 + (c - 32) / 3 : 48 + (c - 80) / 5);
      if (m != mprev) {                    // wave-uniform branch
        const ushort* wp = wb + ((size_t)((m * 32 + s * 8 + rg) * NO + ocol)) * 8;
        bw0 = *reinterpret_cast<const bf16x8*>(wp);
        bw1 = *reinterpret_cast<const bf16x8*>(wp + (size_t)4 * NO * 8);
        mprev = m;
      }
      const ushort* xp = xs + (cc * 16 + rb) * KQ;
      const int swzr = ((rb & 7) ^ (cc & 7)) << 3;
      bf16x8 a0 = *reinterpret_cast<const bf16x8*>(xp + ((rg * 8) ^ swzr));
      acc[cc] = __builtin_amdgcn_mfma_f32_16x16x32_bf16(a0, bw0, acc[cc], 0, 0, 0);
      bf16x8 a1 = *reinterpret_cast<const bf16x8*>(xp + ((32 + rg * 8) ^ swzr));
      acc[cc] = __builtin_amdgcn_mfma_f32_16x16x32_bf16(a1, bw1, acc[cc], 0, 0, 0);
    }
  }

  if (c0 < 32) {                           // l=0 irreps: bias b0[m=c][o] (uniform branch)
#pragma unroll
    for (int cc = 0; cc < CW; ++cc) {
      float bv = bias0[(c0 + cc) * NO + ocol];
      acc[cc] += bv;
    }
  }

  const int br0 = bg + rg * 4;             // D row = (lane>>4)*4 + reg
#pragma unroll
  for (int r = 0; r < 4; ++r) {
#pragma unroll
    for (int q = 0; q < CW / 4; ++q) {     // 2 x 16B stores, 32B contiguous per thread
      float4 v = make_float4(acc[4 * q + 0][r], acc[4 * q + 1][r],
                             acc[4 * q + 2][r], acc[4 * q + 3][r]);
      float* dst = out + ((size_t)(br0 + r) * NO + ocol) * NC + (c0 + 4 * q);
      *reinterpret_cast<float4*>(dst) = v;
    }
  }
}

extern "C" void kernel_launch(void* const* d_in, const int* in_sizes, int n_in,
                              void* d_out, int out_size, void* d_ws, size_t ws_size,
                              hipStream_t stream) {
  const float* x  = (const float*)d_in[0];
  const float* w0 = (const float*)d_in[1];
  const float* w1 = (const float*)d_in[2];
  const float* w2 = (const float*)d_in[3];
  const float* b0 = (const float*)d_in[4];
  float* out = (float*)d_out;
  ushort* wb = (ushort*)d_ws;              // 7.34 MB of scratch

  prep_w<<<56 * 32, 256, 0, stream>>>(w0, w1, w2, wb);
  e3mix<<<15 * 256, 256, 0, stream>>>(x, wb, b0, out);
}

// Round 5
// 173.589 us; speedup vs baseline: 1.8020x; 1.8020x over previous
//
#include <hip/hip_runtime.h>

typedef __attribute__((ext_vector_type(8))) short bf16x8;
typedef __attribute__((ext_vector_type(4))) float f32x4;
typedef __attribute__((ext_vector_type(8))) unsigned short u16x8;

#define DEVINL __device__ __forceinline__

constexpr int NI = 256;   // input channels (K)
constexpr int NO = 256;   // output channels
constexpr int NC = 120;   // irrep feature width
constexpr int WELEMS = 56 * NO * NI;                 // 3,670,016
constexpr size_t XT_ELEMS = (size_t)NC * 1024 * NI;  // 31,457,280

DEVINL ushort f2bf(float x) {   // round-to-nearest-even fp32 -> bf16 bits
  unsigned u = __float_as_uint(x);
  u += 0x7FFFu + ((u >> 16) & 1u);
  return (ushort)(u >> 16);
}

// ---- prep: wb[((m*32 + k/8)*256 + o)*8 + k%8] = bf16(W_m[o][k]) ----
__global__ __launch_bounds__(256) void prep_w(const float* __restrict__ w0,
                                              const float* __restrict__ w1,
                                              const float* __restrict__ w2,
                                              ushort* __restrict__ wb) {
  const int m = blockIdx.x >> 5;        // 0..55
  const int kc = blockIdx.x & 31;       // k-chunk of 8
  const int o = threadIdx.x;            // 0..255
  const float* src;
  if (m < 32)      src = w0 + ((size_t)(m * NO + o)) * NI;
  else if (m < 48) src = w1 + ((size_t)((m - 32) * NO + o)) * NI;
  else             src = w2 + ((size_t)((m - 48) * NO + o)) * NI;
  src += kc * 8;
  float4 a = *reinterpret_cast<const float4*>(src);
  float4 b = *reinterpret_cast<const float4*>(src + 4);
  u16x8 p = { f2bf(a.x), f2bf(a.y), f2bf(a.z), f2bf(a.w),
              f2bf(b.x), f2bf(b.y), f2bf(b.z), f2bf(b.w) };
  *reinterpret_cast<u16x8*>(wb + ((size_t)(blockIdx.x * 256 + o)) * 8) = p;
}

// ---- pass 1: x [1024][256 i][120 c] f32 -> xT [120 c][1024 b][256 i] bf16 ----
// Fully contiguous reads (120 KB/block) and writes (512 B runs per c).
__global__ __launch_bounds__(256) void xpose(const float* __restrict__ x,
                                             ushort* __restrict__ xt) {
  __shared__ ushort tl[120 * 256];     // addr(c,i) = c*256 + (i ^ ((c&7)<<3)), 60 KB
  const int b = blockIdx.x;            // 1024 blocks, one b each
  const int t = threadIdx.x;
  const float* xb = x + (size_t)b * (NI * NC);
#pragma unroll
  for (int j = 0; j < 30; ++j) {       // 30*1024 = 30720 elems, f32x4 coalesced
    const int e = j * 1024 + t * 4;    // c = e%120 is a multiple of 4 -> no row wrap
    f32x4 v = *reinterpret_cast<const f32x4*>(xb + e);
    const int i = e / 120, c = e % 120;
#pragma unroll
    for (int k = 0; k < 4; ++k)
      tl[(c + k) * 256 + (i ^ (((c + k) & 7) << 3))] = f2bf(v[k]);
  }
  __syncthreads();
  ushort* dst = xt + (size_t)b * 256;
#pragma unroll
  for (int q = 0; q < 15; ++q) {       // 3840 chunks of 8 i, 15 per thread
    const int chunk = q * 256 + t;
    const int c = chunk >> 5, i0 = (chunk & 31) * 8;
    u16x8 v = *reinterpret_cast<const u16x8*>(&tl[c * 256 + (i0 ^ ((c & 7) << 3))]);
    *reinterpret_cast<u16x8*>(dst + (size_t)c * (1024 * NI) + i0) = v;
  }
}

// ---- pass 2: block = [8 c] x [16 b] x [256 o], 8 waves, K in 4 stages via LDS ----
// FROMX=0: stage from contiguous bf16 xT (fast). FROMX=1: direct from x (ws fallback).
template<int FROMX>
__global__ __launch_bounds__(512, 4) void e3mix2(const float* __restrict__ x,
                                                 const ushort* __restrict__ xt,
                                                 const ushort* __restrict__ wb,
                                                 const float* __restrict__ bias0,
                                                 float* __restrict__ out) {
  __shared__ ushort xs[8 * 16 * 64];   // [cc][b][64 k] rows 128 B, XOR swz, 16 KB
  const int bid = blockIdx.x;          // 960 = 15 ct * 64 bt
  const int ct = bid % 15, bt = bid / 15;
  const int c0 = ct * 8, bg = bt * 16;

  const int t = threadIdx.x, lane = t & 63, wid = t >> 6;
  const int sb = lane >> 2, sp = lane & 3;     // staging: c=wid, b=sb, k-part=sp
  const int rb = lane & 15, rg = lane >> 4;    // frag row (b), k-group
  const int oc = wid * 16 + (lane & 15);       // o-col, + of*128

  // staging LDS addr (stage-invariant): element k stored at k ^ ((b&7)<<3) in row
  const int srow = (wid * 16 + sb) * 64;
  const int sk0 = (sp * 16) ^ ((sb & 7) << 3);
  const int sk1 = (sp * 16 + 8) ^ ((sb & 7) << 3);
  const ushort* xsrc = FROMX ? nullptr
      : xt + (size_t)(c0 + wid) * (1024 * NI) + (size_t)(bg + sb) * NI + sp * 16;

  f32x4 acc[8][2];
#pragma unroll
  for (int i = 0; i < 8; ++i) { acc[i][0] = (f32x4)0.0f; acc[i][1] = (f32x4)0.0f; }

  u16x8 v0 = {}, v1 = {};
  if constexpr (!FROMX) {              // preload stage 0
    v0 = *reinterpret_cast<const u16x8*>(xsrc);
    v1 = *reinterpret_cast<const u16x8*>(xsrc + 8);
  }
  bf16x8 w00 = {}, w01 = {}, w10 = {}, w11 = {};

#pragma unroll 1
  for (int s = 0; s < 4; ++s) {
    if (s) __syncthreads();            // compute(s-1) done before overwrite
    if constexpr (FROMX) {             // fallback: strided scalar gather from x
      const float* src = x + (size_t)(bg + sb) * (NI * NC)
                           + (size_t)(s * 64 + sp * 16) * NC + (c0 + wid);
#pragma unroll
      for (int jj = 0; jj < 8; ++jj) v0[jj] = f2bf(src[jj * NC]);
#pragma unroll
      for (int jj = 0; jj < 8; ++jj) v1[jj] = f2bf(src[(8 + jj) * NC]);
    }
    *reinterpret_cast<u16x8*>(&xs[srow + sk0]) = v0;
    *reinterpret_cast<u16x8*>(&xs[srow + sk1]) = v1;
    __syncthreads();
    if constexpr (!FROMX) {
      if (s < 3) {                     // prefetch next stage during compute
        v0 = *reinterpret_cast<const u16x8*>(xsrc + (s + 1) * 64);
        v1 = *reinterpret_cast<const u16x8*>(xsrc + (s + 1) * 64 + 8);
      }
    }

    int mprev = -1;
#pragma unroll
    for (int cc = 0; cc < 8; ++cc) {
      const int c = c0 + cc;
      const int m = c < 32 ? c : (c < 80 ? 32 + (c - 32) / 3 : 48 + (c - 80) / 5);
      if (m != mprev) {                // wave-uniform branch; loads are independent
        const ushort* wp = wb + ((size_t)((m * 32 + s * 8 + rg) * NO + oc)) * 8;
        w00 = *reinterpret_cast<const bf16x8*>(wp);                       // half0, of0
        w10 = *reinterpret_cast<const bf16x8*>(wp + (size_t)4 * NO * 8);  // half1, of0
        w01 = *reinterpret_cast<const bf16x8*>(wp + 128 * 8);             // half0, of1
        w11 = *reinterpret_cast<const bf16x8*>(wp + (size_t)4 * NO * 8 + 128 * 8);
        mprev = m;
      }
      const ushort* xp = xs + (cc * 16 + rb) * 64;
      const int sz = (rb & 7) << 3;
      bf16x8 a0 = *reinterpret_cast<const bf16x8*>(xp + ((rg * 8) ^ sz));
      bf16x8 a1 = *reinterpret_cast<const bf16x8*>(xp + ((32 + rg * 8) ^ sz));
      acc[cc][0] = __builtin_amdgcn_mfma_f32_16x16x32_bf16(a0, w00, acc[cc][0], 0, 0, 0);
      acc[cc][0] = __builtin_amdgcn_mfma_f32_16x16x32_bf16(a1, w10, acc[cc][0], 0, 0, 0);
      acc[cc][1] = __builtin_amdgcn_mfma_f32_16x16x32_bf16(a0, w01, acc[cc][1], 0, 0, 0);
      acc[cc][1] = __builtin_amdgcn_mfma_f32_16x16x32_bf16(a1, w11, acc[cc][1], 0, 0, 0);
    }
  }

  if (c0 < 32) {                       // l=0 irreps: bias b0[m=c][o]
#pragma unroll
    for (int cc = 0; cc < 8; ++cc) {
      acc[cc][0] += bias0[(c0 + cc) * NO + oc];
      acc[cc][1] += bias0[(c0 + cc) * NO + oc + 128];
    }
  }

  const int br0 = bg + rg * 4;         // D row = (lane>>4)*4 + reg
#pragma unroll
  for (int of = 0; of < 2; ++of)
#pragma unroll
    for (int r = 0; r < 4; ++r) {
      float4 va = make_float4(acc[0][of][r], acc[1][of][r], acc[2][of][r], acc[3][of][r]);
      float4 vb = make_float4(acc[4][of][r], acc[5][of][r], acc[6][of][r], acc[7][of][r]);
      float* dst = out + ((size_t)(br0 + r) * NO + oc + of * 128) * NC + c0;
      *reinterpret_cast<float4*>(dst) = va;
      *reinterpret_cast<float4*>(dst + 4) = vb;
    }
}

extern "C" void kernel_launch(void* const* d_in, const int* in_sizes, int n_in,
                              void* d_out, int out_size, void* d_ws, size_t ws_size,
                              hipStream_t stream) {
  const float* x  = (const float*)d_in[0];
  const float* w0 = (const float*)d_in[1];
  const float* w1 = (const float*)d_in[2];
  const float* w2 = (const float*)d_in[3];
  const float* b0 = (const float*)d_in[4];
  float* out = (float*)d_out;
  ushort* wb = (ushort*)d_ws;                       // 7.34 MB
  ushort* xt = wb + WELEMS;                         // +62.9 MB

  prep_w<<<56 * 32, 256, 0, stream>>>(w0, w1, w2, wb);
  const bool big = ws_size >= (size_t)2 * (WELEMS + XT_ELEMS);
  if (big) {
    xpose<<<1024, 256, 0, stream>>>(x, xt);
    e3mix2<0><<<960, 512, 0, stream>>>(x, xt, wb, b0, out);
  } else {
    e3mix2<1><<<960, 512, 0, stream>>>(x, nullptr, wb, b0, out);
  }
}